// Round 7
// baseline (151.947 us; speedup 1.0000x reference)
//
#include <hip/hip_runtime.h>
#include <hip/hip_fp16.h>

#define DIN 128
#define DH 64
#define SCAN_TILE 1024
#define NBINS 512      // bin = dst >> 7 ; n=50000 -> bins 0..390 used
#define BIN_SHIFT 7
#define BIN_NODES 128
#define ETILE 4096     // edges per histogram/scatter block
#define EBUF 4096      // LDS edge buffer per bin (avg fill ~2046)

__device__ inline unsigned pack_half2(float a, float b) {
  __half2 h = __floats2half2_rn(a, b);
  return *(unsigned*)&h;
}
__device__ inline float2 unpack_half2(unsigned u) {
  __half2 h = *(__half2*)&u;
  return __half22float2(h);
}

// ---------------- binning pass A: per-block histogram ----------------
__global__ __launch_bounds__(256) void k_hist(const int* __restrict__ dst,
                                              int* __restrict__ histMat, int e, int nblk) {
  __shared__ int h[NBINS];
  int t = threadIdx.x;
  for (int i = t; i < NBINS; i += 256) h[i] = 0;
  __syncthreads();
  int base = blockIdx.x * ETILE;
  for (int i = base + t; i < base + ETILE; i += 256)
    if (i < e) atomicAdd(&h[dst[i] >> BIN_SHIFT], 1);
  __syncthreads();
  for (int i = t; i < NBINS; i += 256) histMat[i * nblk + blockIdx.x] = h[i];
}

// ---------------- hierarchical exclusive scan (histMat) ----------------
__global__ __launch_bounds__(256) void k_scan_part(const int* __restrict__ in,
                                                   int* __restrict__ partials, int n) {
  __shared__ int red[256];
  int t = threadIdx.x;
  int base = blockIdx.x * SCAN_TILE + t * 4;
  int s = 0;
#pragma unroll
  for (int j = 0; j < 4; ++j) { int i = base + j; if (i < n) s += in[i]; }
  red[t] = s;
  __syncthreads();
  for (int ofs = 128; ofs > 0; ofs >>= 1) {
    if (t < ofs) red[t] += red[t + ofs];
    __syncthreads();
  }
  if (t == 0) partials[blockIdx.x] = red[0];
}

__global__ __launch_bounds__(256) void k_scan_mid(int* __restrict__ partials, int nb) {
  __shared__ int sm[256];
  int t = threadIdx.x;
  int v = (t < nb) ? partials[t] : 0;
  sm[t] = v;
  __syncthreads();
  for (int ofs = 1; ofs < 256; ofs <<= 1) {
    int u = (t >= ofs) ? sm[t - ofs] : 0;
    __syncthreads();
    sm[t] += u;
    __syncthreads();
  }
  if (t < nb) partials[t] = sm[t] - v;  // exclusive
}

__global__ __launch_bounds__(256) void k_scan_emit(int* __restrict__ data,
                                                   const int* __restrict__ partials, int n) {
  __shared__ int red[256];
  int t = threadIdx.x;
  int base = blockIdx.x * SCAN_TILE + t * 4;
  int d[4];
  int s = 0;
#pragma unroll
  for (int j = 0; j < 4; ++j) { int i = base + j; d[j] = (i < n) ? data[i] : 0; s += d[j]; }
  red[t] = s;
  __syncthreads();
  int incl = s;
  for (int ofs = 1; ofs < 256; ofs <<= 1) {
    int u = (t >= ofs) ? red[t - ofs] : 0;
    __syncthreads();
    red[t] += u;
    __syncthreads();
    incl = red[t];
  }
  int run = partials[blockIdx.x] + incl - s;
#pragma unroll
  for (int j = 0; j < 4; ++j) {
    int i = base + j;
    if (i < n) { data[i] = run; run += d[j]; }
  }
}

// ---------------- binning pass B: scatter packed (src<<7|local) --------------
__global__ __launch_bounds__(256) void k_scatter(const int* __restrict__ src,
                                                 const int* __restrict__ dst,
                                                 const int* __restrict__ scanHist,
                                                 int* __restrict__ sp, int e, int nblk) {
  __shared__ int cur[NBINS];
  int t = threadIdx.x;
  for (int i = t; i < NBINS; i += 256) cur[i] = scanHist[i * nblk + blockIdx.x];
  __syncthreads();
  int base = blockIdx.x * ETILE;
  for (int i = base + t; i < base + ETILE; i += 256)
    if (i < e) {
      int d = dst[i];
      int pos = atomicAdd(&cur[d >> BIN_SHIFT], 1);
      sp[pos] = (src[i] << BIN_SHIFT) | (d & (BIN_NODES - 1));
    }
}

// ---------------- pass C (fused): per-bin deg + local scan -> off/dinv/srcs --
__global__ __launch_bounds__(256) void k_bincsr(const int* __restrict__ sp,
                                                const int* __restrict__ scanHist,
                                                int* __restrict__ off,
                                                float* __restrict__ dinv,
                                                int* __restrict__ srcs,
                                                int n, int e, int nblk) {
  __shared__ int dl[BIN_NODES];
  __shared__ int sc[BIN_NODES];
  __shared__ int curl[BIN_NODES];
  __shared__ int ebuf[EBUF];
  int b = blockIdx.x, t = threadIdx.x;
  if (t < BIN_NODES) dl[t] = 0;
  __syncthreads();
  int e0 = scanHist[b * nblk];
  int e1 = (b + 1 < NBINS) ? scanHist[(b + 1) * nblk] : e;
  for (int i = e0 + t; i < e1; i += 256) {
    int u = sp[i];
    int k = i - e0;
    if (k < EBUF) ebuf[k] = u;
    atomicAdd(&dl[u & (BIN_NODES - 1)], 1);
  }
  __syncthreads();
  if (t < BIN_NODES) sc[t] = dl[t];
  __syncthreads();
  for (int ofs = 1; ofs < BIN_NODES; ofs <<= 1) {
    int v = (t < BIN_NODES && t >= ofs) ? sc[t - ofs] : 0;
    __syncthreads();
    if (t < BIN_NODES) sc[t] += v;
    __syncthreads();
  }
  int nbase = b * BIN_NODES;
  if (t < BIN_NODES) {
    int ex = e0 + sc[t] - dl[t];  // global CSR start for this node
    curl[t] = ex;
    int node = nbase + t;
    if (node < n) {
      off[node] = ex;
      dinv[node] = rsqrtf((float)(dl[t] + 1));
    }
  }
  if (b == 0 && t == 0) off[n] = e;
  __syncthreads();
  for (int i = e0 + t; i < e1; i += 256) {
    int k = i - e0;
    int u = (k < EBUF) ? ebuf[k] : sp[i];
    int l = u & (BIN_NODES - 1);
    int pos = atomicAdd(&curl[l], 1);
    srcs[pos] = u >> BIN_SHIFT;
  }
}

// ---------------- register-tiled GEMM: [n,K] @ [K,64] (+bias,+relu) ----------
template <int K, bool RELU, bool BIAS, bool OUTHALF>
__global__ __launch_bounds__(256) void k_gemm_rt(const float* __restrict__ A,
                                                 const float* __restrict__ W,
                                                 const float* __restrict__ bias,
                                                 void* __restrict__ outv, int n) {
  constexpr int KC = 32;
  constexpr int MP = 132;  // 128 + 4 pad
  __shared__ float xsT[KC][MP];
  __shared__ float ws[KC * 64];
  __shared__ float bs[64];
  int t = threadIdx.x;
  if (BIAS && t < 64) bs[t] = bias[t];
  int row0 = blockIdx.x * 128;
  int rg = t >> 4;
  int cg = t & 15;
  int r0 = rg * 8;
  int c0 = cg * 4;
  float4 acc[8];
#pragma unroll
  for (int i = 0; i < 8; ++i) acc[i] = make_float4(0.f, 0.f, 0.f, 0.f);

  int lr = t >> 3;  // staging row 0..31
  int kq = t & 7;   // staging k-quad

  for (int kc = 0; kc < K; kc += KC) {
#pragma unroll
    for (int it = 0; it < 4; ++it) {
      int r = it * 32 + lr;
      int gr = row0 + r;
      float4 v = make_float4(0.f, 0.f, 0.f, 0.f);
      if (gr < n) v = *(const float4*)&A[(size_t)gr * K + kc + kq * 4];
      xsT[kq * 4 + 0][r] = v.x;
      xsT[kq * 4 + 1][r] = v.y;
      xsT[kq * 4 + 2][r] = v.z;
      xsT[kq * 4 + 3][r] = v.w;
    }
#pragma unroll
    for (int j = 0; j < 8; ++j) {
      int idx = t + j * 256;
      ws[idx] = W[(size_t)kc * 64 + idx];
    }
    __syncthreads();
#pragma unroll
    for (int k = 0; k < KC; ++k) {
      float4 xa = *(const float4*)&xsT[k][r0];
      float4 xb = *(const float4*)&xsT[k][r0 + 4];
      float4 wv = *(const float4*)&ws[k * 64 + c0];
      float xr[8] = {xa.x, xa.y, xa.z, xa.w, xb.x, xb.y, xb.z, xb.w};
#pragma unroll
      for (int i = 0; i < 8; ++i) {
        acc[i].x = fmaf(xr[i], wv.x, acc[i].x);
        acc[i].y = fmaf(xr[i], wv.y, acc[i].y);
        acc[i].z = fmaf(xr[i], wv.z, acc[i].z);
        acc[i].w = fmaf(xr[i], wv.w, acc[i].w);
      }
    }
    __syncthreads();
  }

  float4 bv = make_float4(0.f, 0.f, 0.f, 0.f);
  if (BIAS) bv = *(const float4*)&bs[c0];
#pragma unroll
  for (int i = 0; i < 8; ++i) {
    int gr = row0 + r0 + i;
    if (gr < n) {
      float4 o = acc[i];
      o.x += bv.x; o.y += bv.y; o.z += bv.z; o.w += bv.w;
      if (RELU) {
        o.x = fmaxf(o.x, 0.f); o.y = fmaxf(o.y, 0.f);
        o.z = fmaxf(o.z, 0.f); o.w = fmaxf(o.w, 0.f);
      }
      if (OUTHALF) {
        uint2 u;
        u.x = pack_half2(o.x, o.y);
        u.y = pack_half2(o.z, o.w);
        *(uint2*)&((__half*)outv)[(size_t)gr * 64 + c0] = u;
      } else {
        *(float4*)&((float*)outv)[(size_t)gr * 64 + c0] = o;
      }
    }
  }
}

// ---------------- fused MLP head: p = relu(z@Wp1+bp1)@Wp2+bp2, one kernel ----
// 256 thr, 128-row tile, per-thread 8x4; T exchanged transposed via LDS.
__global__ __launch_bounds__(256) void k_mlp_rt(const float* __restrict__ z,
                                                const float* __restrict__ Wp1,
                                                const float* __restrict__ bp1,
                                                const float* __restrict__ Wp2,
                                                const float* __restrict__ bp2,
                                                float* __restrict__ p, int n) {
  constexpr int KC = 32;
  constexpr int MP = 132;
  __shared__ float xsT[KC][MP];   // 16.9 KB (z staging)
  __shared__ float ws[KC * 64];   // 8 KB (weight chunk)
  __shared__ float TsT[64][MP];   // 33.8 KB (T transposed)
  int t = threadIdx.x;
  int row0 = blockIdx.x * 128;
  int rg = t >> 4, cg = t & 15;
  int r0 = rg * 8, c0 = cg * 4;
  int lr = t >> 3, kq = t & 7;

  float4 acc[8];
#pragma unroll
  for (int i = 0; i < 8; ++i) acc[i] = make_float4(0.f, 0.f, 0.f, 0.f);

  // ---- phase 1: T = relu(z@Wp1 + bp1) ----
  for (int kc = 0; kc < 64; kc += KC) {
#pragma unroll
    for (int it = 0; it < 4; ++it) {
      int r = it * 32 + lr;
      int gr = row0 + r;
      float4 v = make_float4(0.f, 0.f, 0.f, 0.f);
      if (gr < n) v = *(const float4*)&z[(size_t)gr * 64 + kc + kq * 4];
      xsT[kq * 4 + 0][r] = v.x;
      xsT[kq * 4 + 1][r] = v.y;
      xsT[kq * 4 + 2][r] = v.z;
      xsT[kq * 4 + 3][r] = v.w;
    }
#pragma unroll
    for (int j = 0; j < 8; ++j) {
      int idx = t + j * 256;
      ws[idx] = Wp1[(size_t)kc * 64 + idx];
    }
    __syncthreads();
#pragma unroll
    for (int k = 0; k < KC; ++k) {
      float4 xa = *(const float4*)&xsT[k][r0];
      float4 xb = *(const float4*)&xsT[k][r0 + 4];
      float4 wv = *(const float4*)&ws[k * 64 + c0];
      float xr[8] = {xa.x, xa.y, xa.z, xa.w, xb.x, xb.y, xb.z, xb.w};
#pragma unroll
      for (int i = 0; i < 8; ++i) {
        acc[i].x = fmaf(xr[i], wv.x, acc[i].x);
        acc[i].y = fmaf(xr[i], wv.y, acc[i].y);
        acc[i].z = fmaf(xr[i], wv.z, acc[i].z);
        acc[i].w = fmaf(xr[i], wv.w, acc[i].w);
      }
    }
    __syncthreads();
  }
  float4 b1v = *(const float4*)&bp1[c0];
#pragma unroll
  for (int i = 0; i < 8; ++i) {
    int r = r0 + i;
    TsT[c0 + 0][r] = fmaxf(acc[i].x + b1v.x, 0.f);
    TsT[c0 + 1][r] = fmaxf(acc[i].y + b1v.y, 0.f);
    TsT[c0 + 2][r] = fmaxf(acc[i].z + b1v.z, 0.f);
    TsT[c0 + 3][r] = fmaxf(acc[i].w + b1v.w, 0.f);
  }

  // ---- phase 2: p = T@Wp2 + bp2 ----
  float4 acc2[8];
#pragma unroll
  for (int i = 0; i < 8; ++i) acc2[i] = make_float4(0.f, 0.f, 0.f, 0.f);
  for (int kc = 0; kc < 64; kc += KC) {
    __syncthreads();  // TsT complete (first iter) / ws reads done (second iter)
#pragma unroll
    for (int j = 0; j < 8; ++j) {
      int idx = t + j * 256;
      ws[idx] = Wp2[(size_t)kc * 64 + idx];
    }
    __syncthreads();
#pragma unroll
    for (int k = 0; k < KC; ++k) {
      float4 xa = *(const float4*)&TsT[kc + k][r0];
      float4 xb = *(const float4*)&TsT[kc + k][r0 + 4];
      float4 wv = *(const float4*)&ws[k * 64 + c0];
      float xr[8] = {xa.x, xa.y, xa.z, xa.w, xb.x, xb.y, xb.z, xb.w};
#pragma unroll
      for (int i = 0; i < 8; ++i) {
        acc2[i].x = fmaf(xr[i], wv.x, acc2[i].x);
        acc2[i].y = fmaf(xr[i], wv.y, acc2[i].y);
        acc2[i].z = fmaf(xr[i], wv.z, acc2[i].z);
        acc2[i].w = fmaf(xr[i], wv.w, acc2[i].w);
      }
    }
  }
  float4 b2v = *(const float4*)&bp2[c0];
#pragma unroll
  for (int i = 0; i < 8; ++i) {
    int gr = row0 + r0 + i;
    if (gr < n) {
      float4 o = acc2[i];
      o.x += b2v.x; o.y += b2v.y; o.z += b2v.z; o.w += b2v.w;
      *(float4*)&p[(size_t)gr * 64 + c0] = o;
    }
  }
}

// ---------------- CSR gather-aggregate (fp16 table): 16 edges in flight ------
__global__ __launch_bounds__(256) void k_agg(const __half* __restrict__ gh,
                                             const int* __restrict__ off,
                                             const int* __restrict__ srcs,
                                             const float* __restrict__ dinv,
                                             const float* __restrict__ bias,
                                             float* __restrict__ out, int n, int relu) {
  int gid = blockIdx.x * 4 + (threadIdx.x >> 6);
  if (gid >= n) return;
  gid = __builtin_amdgcn_readfirstlane(gid);
  int lane = threadIdx.x & 63;
  int grp = lane >> 4;         // 0..3: edge slot
  int d4 = (lane & 15) * 4;    // feature quad
  float di = dinv[gid];
  float4 acc = make_float4(0.f, 0.f, 0.f, 0.f);
  if (grp == 0) {  // self-loop counted once
    uint2 raw = *(const uint2*)(gh + (size_t)gid * DH + d4);
    float2 f0 = unpack_half2(raw.x), f1 = unpack_half2(raw.y);
    float s = di * di;
    acc.x = f0.x * s; acc.y = f0.y * s; acc.z = f1.x * s; acc.w = f1.y * s;
  }
  int b0 = off[gid], b1 = off[gid + 1];
  int j = b0 + grp;
  for (; j + 12 < b1; j += 16) {  // 4 rows in flight per group
    int s0 = srcs[j], s1 = srcs[j + 4], s2 = srcs[j + 8], s3 = srcs[j + 12];
    float w0 = dinv[s0] * di, w1 = dinv[s1] * di;
    float w2 = dinv[s2] * di, w3 = dinv[s3] * di;
    uint2 r0 = *(const uint2*)(gh + (size_t)s0 * DH + d4);
    uint2 r1 = *(const uint2*)(gh + (size_t)s1 * DH + d4);
    uint2 r2 = *(const uint2*)(gh + (size_t)s2 * DH + d4);
    uint2 r3 = *(const uint2*)(gh + (size_t)s3 * DH + d4);
    float2 a0 = unpack_half2(r0.x), a1 = unpack_half2(r0.y);
    float2 c0 = unpack_half2(r1.x), c1 = unpack_half2(r1.y);
    float2 e0 = unpack_half2(r2.x), e1 = unpack_half2(r2.y);
    float2 g0 = unpack_half2(r3.x), g1 = unpack_half2(r3.y);
    acc.x = fmaf(a0.x, w0, acc.x); acc.y = fmaf(a0.y, w0, acc.y);
    acc.z = fmaf(a1.x, w0, acc.z); acc.w = fmaf(a1.y, w0, acc.w);
    acc.x = fmaf(c0.x, w1, acc.x); acc.y = fmaf(c0.y, w1, acc.y);
    acc.z = fmaf(c1.x, w1, acc.z); acc.w = fmaf(c1.y, w1, acc.w);
    acc.x = fmaf(e0.x, w2, acc.x); acc.y = fmaf(e0.y, w2, acc.y);
    acc.z = fmaf(e1.x, w2, acc.z); acc.w = fmaf(e1.y, w2, acc.w);
    acc.x = fmaf(g0.x, w3, acc.x); acc.y = fmaf(g0.y, w3, acc.y);
    acc.z = fmaf(g1.x, w3, acc.z); acc.w = fmaf(g1.y, w3, acc.w);
  }
  for (; j + 4 < b1; j += 8) {
    int sa = srcs[j], sb = srcs[j + 4];
    float wa = dinv[sa] * di, wb = dinv[sb] * di;
    uint2 ra = *(const uint2*)(gh + (size_t)sa * DH + d4);
    uint2 rb = *(const uint2*)(gh + (size_t)sb * DH + d4);
    float2 a0 = unpack_half2(ra.x), a1 = unpack_half2(ra.y);
    float2 c0 = unpack_half2(rb.x), c1 = unpack_half2(rb.y);
    acc.x = fmaf(a0.x, wa, acc.x); acc.y = fmaf(a0.y, wa, acc.y);
    acc.z = fmaf(a1.x, wa, acc.z); acc.w = fmaf(a1.y, wa, acc.w);
    acc.x = fmaf(c0.x, wb, acc.x); acc.y = fmaf(c0.y, wb, acc.y);
    acc.z = fmaf(c1.x, wb, acc.z); acc.w = fmaf(c1.y, wb, acc.w);
  }
  if (j < b1) {
    int s = srcs[j];
    float w = dinv[s] * di;
    uint2 r = *(const uint2*)(gh + (size_t)s * DH + d4);
    float2 f0 = unpack_half2(r.x), f1 = unpack_half2(r.y);
    acc.x = fmaf(f0.x, w, acc.x); acc.y = fmaf(f0.y, w, acc.y);
    acc.z = fmaf(f1.x, w, acc.z); acc.w = fmaf(f1.y, w, acc.w);
  }
  acc.x += __shfl_xor(acc.x, 16, 64); acc.x += __shfl_xor(acc.x, 32, 64);
  acc.y += __shfl_xor(acc.y, 16, 64); acc.y += __shfl_xor(acc.y, 32, 64);
  acc.z += __shfl_xor(acc.z, 16, 64); acc.z += __shfl_xor(acc.z, 32, 64);
  acc.w += __shfl_xor(acc.w, 16, 64); acc.w += __shfl_xor(acc.w, 32, 64);
  if (lane < 16) {
    float4 bv = *(const float4*)&bias[d4];
    acc.x += bv.x; acc.y += bv.y; acc.z += bv.z; acc.w += bv.w;
    if (relu) {
      acc.x = fmaxf(acc.x, 0.f); acc.y = fmaxf(acc.y, 0.f);
      acc.z = fmaxf(acc.z, 0.f); acc.w = fmaxf(acc.w, 0.f);
    }
    *(float4*)&out[(size_t)gid * DH + d4] = acc;
  }
}

extern "C" void kernel_launch(void* const* d_in, const int* in_sizes, int n_in,
                              void* d_out, int out_size, void* d_ws, size_t ws_size,
                              hipStream_t stream) {
  const float* x   = (const float*)d_in[0];
  const int*   ei  = (const int*)d_in[1];
  const float* W1  = (const float*)d_in[2];
  const float* b1  = (const float*)d_in[3];
  const float* W2  = (const float*)d_in[4];
  const float* b2  = (const float*)d_in[5];
  const float* Wp1 = (const float*)d_in[6];
  const float* bp1 = (const float*)d_in[7];
  const float* Wp2 = (const float*)d_in[8];
  const float* bp2 = (const float*)d_in[9];

  int n = in_sizes[0] / DIN;   // 50000
  int e = in_sizes[1] / 2;     // 800000
  const int* src = ei;
  const int* dst = ei + e;

  int nblk = (e + ETILE - 1) / ETILE;           // 196
  int nbBins = (n + BIN_NODES - 1) / BIN_NODES; // 391

  // workspace layout
  char* ws = (char*)d_ws;
  __half* gtab   = (__half*)ws;                                   // n*64 fp16 = 6.4MB
  int*    off    = (int*)(ws + ((size_t)13 << 20));
  float*  dinv   = (float*)(ws + ((size_t)13 << 20) + (1 << 18));
  int*    parts  = (int*)(ws + ((size_t)13 << 20) + (2 << 18));
  int*    histMat= (int*)(ws + ((size_t)13 << 20) + (3 << 18));   // ~392KB
  int*    sp     = (int*)(ws + ((size_t)13 << 20) + (5 << 18));   // e i32 = 3.2MB
  int*    srcs   = sp + e;                                        // e i32 = 3.2MB

  float* zout = (float*)d_out;
  float* pout = zout + (size_t)n * DH;  // scratch for h, then final p

  int nHist = NBINS * nblk;
  int nbH = (nHist + SCAN_TILE - 1) / SCAN_TILE;
  int gG = (n + 127) / 128;  // 391

  // ---- binning CSR build ----
  k_hist<<<nblk, 256, 0, stream>>>(dst, histMat, e, nblk);
  k_scan_part<<<nbH, 256, 0, stream>>>(histMat, parts, nHist);
  k_scan_mid<<<1, 256, 0, stream>>>(parts, nbH);
  k_scan_emit<<<nbH, 256, 0, stream>>>(histMat, parts, nHist);
  k_scatter<<<nblk, 256, 0, stream>>>(src, dst, histMat, sp, e, nblk);
  k_bincsr<<<nbBins, 256, 0, stream>>>(sp, histMat, off, dinv, srcs, n, e, nblk);

  // ---- layer 1: g1 = x@W1 (fp16) ; h = relu(agg(g1) + b1) -> pout ----
  k_gemm_rt<DIN, false, false, true><<<gG, 256, 0, stream>>>(x, W1, nullptr, gtab, n);
  k_agg<<<(n + 3) / 4, 256, 0, stream>>>(gtab, off, srcs, dinv, b1, pout, n, 1);

  // ---- layer 2: g2 = h@W2 (fp16) ; z = agg(g2) + b2 -> zout ----
  k_gemm_rt<DH, false, false, true><<<gG, 256, 0, stream>>>(pout, W2, nullptr, gtab, n);
  k_agg<<<(n + 3) / 4, 256, 0, stream>>>(gtab, off, srcs, dinv, b2, zout, n, 0);

  // ---- head: p = relu(z@Wp1+bp1)@Wp2+bp2, fused ----
  k_mlp_rt<<<gG, 256, 0, stream>>>(zout, Wp1, bp1, Wp2, bp2, pout, n);
}

// Round 9
// 145.132 us; speedup vs baseline: 1.0470x; 1.0470x over previous
//
#include <hip/hip_runtime.h>
#include <hip/hip_fp16.h>

#define DIN 128
#define DH 64
#define NBINS 512      // bin = dst >> 7 ; n=50000 -> bins 0..390 used
#define BIN_SHIFT 7
#define BIN_NODES 128
#define ETILE 4096     // edges per histogram/scatter block
#define EBUF 4096      // LDS edge buffer per bin (avg fill ~2046)

__device__ inline unsigned pack_half2(float a, float b) {
  __half2 h = __floats2half2_rn(a, b);
  return *(unsigned*)&h;
}
__device__ inline float2 unpack_half2(unsigned u) {
  __half2 h = *(__half2*)&u;
  return __half22float2(h);
}

// ---------------- zero helper (capture-safe) ----------------
__global__ __launch_bounds__(512) void k_zero(int* __restrict__ p, int n) {
  int i = blockIdx.x * blockDim.x + threadIdx.x;
  if (i < n) p[i] = 0;
}

// ---------------- A: fused  gemm1 (x@W1 -> fp16 g1)  ||  bin histogram ------
__global__ __launch_bounds__(256) void k_fusedA(const float* __restrict__ x,
                                                const float* __restrict__ W1,
                                                __half* __restrict__ g1,
                                                const int* __restrict__ dst,
                                                int* __restrict__ binTot,
                                                int n, int e, int gG) {
  __shared__ float xsT[32][132];
  __shared__ float ws[32 * 64];
  __shared__ int hh[NBINS];
  int t = threadIdx.x;
  int bid = blockIdx.x;

  if (bid >= gG) {  // ---- histogram part ----
    int b = bid - gG;
    for (int i = t; i < NBINS; i += 256) hh[i] = 0;
    __syncthreads();
    int lo = b * ETILE, hi = lo + ETILE; if (hi > e) hi = e;
    for (int i = lo + t; i < hi; i += 256) atomicAdd(&hh[dst[i] >> BIN_SHIFT], 1);
    __syncthreads();
    for (int i = t; i < NBINS; i += 256) if (hh[i]) atomicAdd(&binTot[i], hh[i]);
    return;
  }

  // ---- gemm part: [n,128]@[128,64] -> fp16 ----
  int row0 = bid * 128;
  int rg = t >> 4, cg = t & 15;
  int r0 = rg * 8, c0 = cg * 4;
  int lr = t >> 3, kq = t & 7;
  float4 acc[8];
#pragma unroll
  for (int i = 0; i < 8; ++i) acc[i] = make_float4(0.f, 0.f, 0.f, 0.f);

  for (int kc = 0; kc < DIN; kc += 32) {
#pragma unroll
    for (int it = 0; it < 4; ++it) {
      int r = it * 32 + lr;
      int gr = row0 + r;
      float4 v = make_float4(0.f, 0.f, 0.f, 0.f);
      if (gr < n) v = *(const float4*)&x[(size_t)gr * DIN + kc + kq * 4];
      xsT[kq * 4 + 0][r] = v.x;
      xsT[kq * 4 + 1][r] = v.y;
      xsT[kq * 4 + 2][r] = v.z;
      xsT[kq * 4 + 3][r] = v.w;
    }
#pragma unroll
    for (int j = 0; j < 8; ++j) ws[t + j * 256] = W1[(size_t)kc * 64 + t + j * 256];
    __syncthreads();
#pragma unroll
    for (int k = 0; k < 32; ++k) {
      float4 xa = *(const float4*)&xsT[k][r0];
      float4 xb = *(const float4*)&xsT[k][r0 + 4];
      float4 wv = *(const float4*)&ws[k * 64 + c0];
      float xr[8] = {xa.x, xa.y, xa.z, xa.w, xb.x, xb.y, xb.z, xb.w};
#pragma unroll
      for (int i = 0; i < 8; ++i) {
        acc[i].x = fmaf(xr[i], wv.x, acc[i].x);
        acc[i].y = fmaf(xr[i], wv.y, acc[i].y);
        acc[i].z = fmaf(xr[i], wv.z, acc[i].z);
        acc[i].w = fmaf(xr[i], wv.w, acc[i].w);
      }
    }
    __syncthreads();
  }
#pragma unroll
  for (int i = 0; i < 8; ++i) {
    int gr = row0 + r0 + i;
    if (gr < n) {
      uint2 u;
      u.x = pack_half2(acc[i].x, acc[i].y);
      u.y = pack_half2(acc[i].z, acc[i].w);
      *(uint2*)&g1[(size_t)gr * 64 + c0] = u;
    }
  }
}

// ---------------- B: scan 512 bin totals -> binOff, init binCur --------------
__global__ __launch_bounds__(512) void k_binscan(const int* __restrict__ binTot,
                                                 int* __restrict__ binOff,
                                                 int* __restrict__ binCur, int e) {
  __shared__ int sm[NBINS];
  int t = threadIdx.x;
  int v = binTot[t];
  sm[t] = v;
  __syncthreads();
  for (int ofs = 1; ofs < NBINS; ofs <<= 1) {
    int u = (t >= ofs) ? sm[t - ofs] : 0;
    __syncthreads();
    sm[t] += u;
    __syncthreads();
  }
  int ex = sm[t] - v;  // exclusive
  binOff[t] = ex;
  binCur[t] = ex;
  if (t == NBINS - 1) binOff[NBINS] = sm[NBINS - 1];
}

// ---------------- C: scatter into bin-grouped order (atomic cursors) ---------
__global__ __launch_bounds__(256) void k_scatter2(const int* __restrict__ src,
                                                  const int* __restrict__ dst,
                                                  int* __restrict__ binCur,
                                                  int* __restrict__ sp, int e) {
  __shared__ int hh[NBINS];
  __shared__ int base[NBINS];
  int t = threadIdx.x;
  for (int i = t; i < NBINS; i += 256) hh[i] = 0;
  __syncthreads();
  int lo = blockIdx.x * ETILE, hi = lo + ETILE; if (hi > e) hi = e;
  for (int i = lo + t; i < hi; i += 256) atomicAdd(&hh[dst[i] >> BIN_SHIFT], 1);
  __syncthreads();
  for (int i = t; i < NBINS; i += 256) {
    int c = hh[i];
    base[i] = c ? atomicAdd(&binCur[i], c) : 0;
  }
  __syncthreads();
  for (int i = t; i < NBINS; i += 256) hh[i] = 0;  // reuse as local cursors
  __syncthreads();
  for (int i = lo + t; i < hi; i += 256) {
    int d = dst[i];
    int bn = d >> BIN_SHIFT;
    int pos = base[bn] + atomicAdd(&hh[bn], 1);
    sp[pos] = (src[i] << BIN_SHIFT) | (d & (BIN_NODES - 1));
  }
}

// ---------------- D: per-bin deg + local scan -> off/dinv/srcs --------------
__global__ __launch_bounds__(256) void k_bincsr(const int* __restrict__ sp,
                                                const int* __restrict__ binOff,
                                                int* __restrict__ off,
                                                float* __restrict__ dinv,
                                                int* __restrict__ srcs,
                                                int n, int e) {
  __shared__ int dl[BIN_NODES];
  __shared__ int sc[BIN_NODES];
  __shared__ int curl[BIN_NODES];
  __shared__ int ebuf[EBUF];
  int b = blockIdx.x, t = threadIdx.x;
  if (t < BIN_NODES) dl[t] = 0;
  __syncthreads();
  int e0 = binOff[b];
  int e1 = binOff[b + 1];
  for (int i = e0 + t; i < e1; i += 256) {
    int u = sp[i];
    int k = i - e0;
    if (k < EBUF) ebuf[k] = u;
    atomicAdd(&dl[u & (BIN_NODES - 1)], 1);
  }
  __syncthreads();
  if (t < BIN_NODES) sc[t] = dl[t];
  __syncthreads();
  for (int ofs = 1; ofs < BIN_NODES; ofs <<= 1) {
    int v = (t < BIN_NODES && t >= ofs) ? sc[t - ofs] : 0;
    __syncthreads();
    if (t < BIN_NODES) sc[t] += v;
    __syncthreads();
  }
  int nbase = b * BIN_NODES;
  if (t < BIN_NODES) {
    int ex = e0 + sc[t] - dl[t];
    curl[t] = ex;
    int node = nbase + t;
    if (node < n) {
      off[node] = ex;
      dinv[node] = rsqrtf((float)(dl[t] + 1));
    }
  }
  if (b == 0 && t == 0) off[n] = e;
  __syncthreads();
  for (int i = e0 + t; i < e1; i += 256) {
    int k = i - e0;
    int u = (k < EBUF) ? ebuf[k] : sp[i];
    int l = u & (BIN_NODES - 1);
    int pos = atomicAdd(&curl[l], 1);
    srcs[pos] = u >> BIN_SHIFT;
  }
}

// ---------------- E/F: CSR gather-aggregate (fp16 in, fp16 out) -------------
__global__ __launch_bounds__(256) void k_agg(const __half* __restrict__ gh,
                                             const int* __restrict__ off,
                                             const int* __restrict__ srcs,
                                             const float* __restrict__ dinv,
                                             const float* __restrict__ bias,
                                             __half* __restrict__ out, int n, int relu) {
  int gid = blockIdx.x * 4 + (threadIdx.x >> 6);
  if (gid >= n) return;
  gid = __builtin_amdgcn_readfirstlane(gid);
  int lane = threadIdx.x & 63;
  int grp = lane >> 4;         // 0..3: edge slot
  int d4 = (lane & 15) * 4;    // feature quad
  float di = dinv[gid];
  float4 acc = make_float4(0.f, 0.f, 0.f, 0.f);
  if (grp == 0) {  // self-loop counted once
    uint2 raw = *(const uint2*)(gh + (size_t)gid * DH + d4);
    float2 f0 = unpack_half2(raw.x), f1 = unpack_half2(raw.y);
    float s = di * di;
    acc.x = f0.x * s; acc.y = f0.y * s; acc.z = f1.x * s; acc.w = f1.y * s;
  }
  int b0 = off[gid], b1 = off[gid + 1];
  int j = b0 + grp;
  for (; j + 12 < b1; j += 16) {  // 4 rows in flight per group
    int s0 = srcs[j], s1 = srcs[j + 4], s2 = srcs[j + 8], s3 = srcs[j + 12];
    float w0 = dinv[s0] * di, w1 = dinv[s1] * di;
    float w2 = dinv[s2] * di, w3 = dinv[s3] * di;
    uint2 r0 = *(const uint2*)(gh + (size_t)s0 * DH + d4);
    uint2 r1 = *(const uint2*)(gh + (size_t)s1 * DH + d4);
    uint2 r2 = *(const uint2*)(gh + (size_t)s2 * DH + d4);
    uint2 r3 = *(const uint2*)(gh + (size_t)s3 * DH + d4);
    float2 a0 = unpack_half2(r0.x), a1 = unpack_half2(r0.y);
    float2 c0 = unpack_half2(r1.x), c1 = unpack_half2(r1.y);
    float2 e0 = unpack_half2(r2.x), e1 = unpack_half2(r2.y);
    float2 g0 = unpack_half2(r3.x), g1 = unpack_half2(r3.y);
    acc.x = fmaf(a0.x, w0, acc.x); acc.y = fmaf(a0.y, w0, acc.y);
    acc.z = fmaf(a1.x, w0, acc.z); acc.w = fmaf(a1.y, w0, acc.w);
    acc.x = fmaf(c0.x, w1, acc.x); acc.y = fmaf(c0.y, w1, acc.y);
    acc.z = fmaf(c1.x, w1, acc.z); acc.w = fmaf(c1.y, w1, acc.w);
    acc.x = fmaf(e0.x, w2, acc.x); acc.y = fmaf(e0.y, w2, acc.y);
    acc.z = fmaf(e1.x, w2, acc.z); acc.w = fmaf(e1.y, w2, acc.w);
    acc.x = fmaf(g0.x, w3, acc.x); acc.y = fmaf(g0.y, w3, acc.y);
    acc.z = fmaf(g1.x, w3, acc.z); acc.w = fmaf(g1.y, w3, acc.w);
  }
  for (; j + 4 < b1; j += 8) {
    int sa = srcs[j], sb = srcs[j + 4];
    float wa = dinv[sa] * di, wb = dinv[sb] * di;
    uint2 ra = *(const uint2*)(gh + (size_t)sa * DH + d4);
    uint2 rb = *(const uint2*)(gh + (size_t)sb * DH + d4);
    float2 a0 = unpack_half2(ra.x), a1 = unpack_half2(ra.y);
    float2 c0 = unpack_half2(rb.x), c1 = unpack_half2(rb.y);
    acc.x = fmaf(a0.x, wa, acc.x); acc.y = fmaf(a0.y, wa, acc.y);
    acc.z = fmaf(a1.x, wa, acc.z); acc.w = fmaf(a1.y, wa, acc.w);
    acc.x = fmaf(c0.x, wb, acc.x); acc.y = fmaf(c0.y, wb, acc.y);
    acc.z = fmaf(c1.x, wb, acc.z); acc.w = fmaf(c1.y, wb, acc.w);
  }
  if (j < b1) {
    int s = srcs[j];
    float w = dinv[s] * di;
    uint2 r = *(const uint2*)(gh + (size_t)s * DH + d4);
    float2 f0 = unpack_half2(r.x), f1 = unpack_half2(r.y);
    acc.x = fmaf(f0.x, w, acc.x); acc.y = fmaf(f0.y, w, acc.y);
    acc.z = fmaf(f1.x, w, acc.z); acc.w = fmaf(f1.y, w, acc.w);
  }
  acc.x += __shfl_xor(acc.x, 16, 64); acc.x += __shfl_xor(acc.x, 32, 64);
  acc.y += __shfl_xor(acc.y, 16, 64); acc.y += __shfl_xor(acc.y, 32, 64);
  acc.z += __shfl_xor(acc.z, 16, 64); acc.z += __shfl_xor(acc.z, 32, 64);
  acc.w += __shfl_xor(acc.w, 16, 64); acc.w += __shfl_xor(acc.w, 32, 64);
  if (lane < 16) {
    if (bias) {
      float4 bv = *(const float4*)&bias[d4];
      acc.x += bv.x; acc.y += bv.y; acc.z += bv.z; acc.w += bv.w;
    }
    if (relu) {
      acc.x = fmaxf(acc.x, 0.f); acc.y = fmaxf(acc.y, 0.f);
      acc.z = fmaxf(acc.z, 0.f); acc.w = fmaxf(acc.w, 0.f);
    }
    uint2 u;
    u.x = pack_half2(acc.x, acc.y);
    u.y = pack_half2(acc.z, acc.w);
    *(uint2*)&out[(size_t)gid * DH + d4] = u;
  }
}

// ---------------- G: fused 3-GEMM head: z = ah@W2+b2 ; p = relu(z@Wp1+bp1)@Wp2+bp2
__global__ __launch_bounds__(256) void k_head3(const __half* __restrict__ ah,
                                               const float* __restrict__ W2,
                                               const float* __restrict__ b2,
                                               const float* __restrict__ Wp1,
                                               const float* __restrict__ bp1,
                                               const float* __restrict__ Wp2,
                                               const float* __restrict__ bp2,
                                               float* __restrict__ z,
                                               float* __restrict__ p, int n) {
  constexpr int KC = 32;
  constexpr int MP = 132;
  __shared__ float xsT[KC][MP];   // ah chunk, transposed
  __shared__ float ws[KC * 64];   // weight chunk
  __shared__ float TsT[64][MP];   // z (then T), transposed
  int t = threadIdx.x;
  int row0 = blockIdx.x * 128;
  int rg = t >> 4, cg = t & 15;
  int r0 = rg * 8, c0 = cg * 4;
  int lr = t >> 3, kq = t & 7;

  // ---- GEMM 1: z = ah @ W2 ----
  float4 acc[8];
#pragma unroll
  for (int i = 0; i < 8; ++i) acc[i] = make_float4(0.f, 0.f, 0.f, 0.f);
  for (int kc = 0; kc < 64; kc += KC) {
#pragma unroll
    for (int it = 0; it < 4; ++it) {
      int r = it * 32 + lr;
      int gr = row0 + r;
      uint2 v = make_uint2(0u, 0u);
      if (gr < n) v = *(const uint2*)(ah + (size_t)gr * 64 + kc + kq * 4);
      float2 f0 = unpack_half2(v.x), f1 = unpack_half2(v.y);
      xsT[kq * 4 + 0][r] = f0.x;
      xsT[kq * 4 + 1][r] = f0.y;
      xsT[kq * 4 + 2][r] = f1.x;
      xsT[kq * 4 + 3][r] = f1.y;
    }
#pragma unroll
    for (int j = 0; j < 8; ++j) ws[t + j * 256] = W2[(size_t)kc * 64 + t + j * 256];
    __syncthreads();
#pragma unroll
    for (int k = 0; k < KC; ++k) {
      float4 xa = *(const float4*)&xsT[k][r0];
      float4 xb = *(const float4*)&xsT[k][r0 + 4];
      float4 wv = *(const float4*)&ws[k * 64 + c0];
      float xr[8] = {xa.x, xa.y, xa.z, xa.w, xb.x, xb.y, xb.z, xb.w};
#pragma unroll
      for (int i = 0; i < 8; ++i) {
        acc[i].x = fmaf(xr[i], wv.x, acc[i].x);
        acc[i].y = fmaf(xr[i], wv.y, acc[i].y);
        acc[i].z = fmaf(xr[i], wv.z, acc[i].z);
        acc[i].w = fmaf(xr[i], wv.w, acc[i].w);
      }
    }
    __syncthreads();
  }
  // z epilogue: bias, write output, stash transposed in TsT
  {
    float4 bv = *(const float4*)&b2[c0];
#pragma unroll
    for (int i = 0; i < 8; ++i) {
      float4 o = acc[i];
      o.x += bv.x; o.y += bv.y; o.z += bv.z; o.w += bv.w;
      int r = r0 + i;
      int gr = row0 + r;
      if (gr < n) *(float4*)&z[(size_t)gr * 64 + c0] = o;
      TsT[c0 + 0][r] = o.x;
      TsT[c0 + 1][r] = o.y;
      TsT[c0 + 2][r] = o.z;
      TsT[c0 + 3][r] = o.w;
    }
  }

  // ---- GEMM 2: T = relu(z @ Wp1 + bp1) ----
  float4 acc2[8];
#pragma unroll
  for (int i = 0; i < 8; ++i) acc2[i] = make_float4(0.f, 0.f, 0.f, 0.f);
  for (int kc = 0; kc < 64; kc += KC) {
    __syncthreads();  // TsT writes visible; prior ws reads done
#pragma unroll
    for (int j = 0; j < 8; ++j) ws[t + j * 256] = Wp1[(size_t)kc * 64 + t + j * 256];
    __syncthreads();
#pragma unroll
    for (int k = 0; k < KC; ++k) {
      float4 xa = *(const float4*)&TsT[kc + k][r0];
      float4 xb = *(const float4*)&TsT[kc + k][r0 + 4];
      float4 wv = *(const float4*)&ws[k * 64 + c0];
      float xr[8] = {xa.x, xa.y, xa.z, xa.w, xb.x, xb.y, xb.z, xb.w};
#pragma unroll
      for (int i = 0; i < 8; ++i) {
        acc2[i].x = fmaf(xr[i], wv.x, acc2[i].x);
        acc2[i].y = fmaf(xr[i], wv.y, acc2[i].y);
        acc2[i].z = fmaf(xr[i], wv.z, acc2[i].z);
        acc2[i].w = fmaf(xr[i], wv.w, acc2[i].w);
      }
    }
  }
  __syncthreads();  // all TsT(z) reads complete
  {
    float4 bv = *(const float4*)&bp1[c0];
#pragma unroll
    for (int i = 0; i < 8; ++i) {
      int r = r0 + i;
      TsT[c0 + 0][r] = fmaxf(acc2[i].x + bv.x, 0.f);
      TsT[c0 + 1][r] = fmaxf(acc2[i].y + bv.y, 0.f);
      TsT[c0 + 2][r] = fmaxf(acc2[i].z + bv.z, 0.f);
      TsT[c0 + 3][r] = fmaxf(acc2[i].w + bv.w, 0.f);
    }
  }

  // ---- GEMM 3: p = T @ Wp2 + bp2 ----
  float4 acc3[8];
#pragma unroll
  for (int i = 0; i < 8; ++i) acc3[i] = make_float4(0.f, 0.f, 0.f, 0.f);
  for (int kc = 0; kc < 64; kc += KC) {
    __syncthreads();  // TsT(T) writes visible; prior ws reads done
#pragma unroll
    for (int j = 0; j < 8; ++j) ws[t + j * 256] = Wp2[(size_t)kc * 64 + t + j * 256];
    __syncthreads();
#pragma unroll
    for (int k = 0; k < KC; ++k) {
      float4 xa = *(const float4*)&TsT[kc + k][r0];
      float4 xb = *(const float4*)&TsT[kc + k][r0 + 4];
      float4 wv = *(const float4*)&ws[k * 64 + c0];
      float xr[8] = {xa.x, xa.y, xa.z, xa.w, xb.x, xb.y, xb.z, xb.w};
#pragma unroll
      for (int i = 0; i < 8; ++i) {
        acc3[i].x = fmaf(xr[i], wv.x, acc3[i].x);
        acc3[i].y = fmaf(xr[i], wv.y, acc3[i].y);
        acc3[i].z = fmaf(xr[i], wv.z, acc3[i].z);
        acc3[i].w = fmaf(xr[i], wv.w, acc3[i].w);
      }
    }
  }
  {
    float4 bv = *(const float4*)&bp2[c0];
#pragma unroll
    for (int i = 0; i < 8; ++i) {
      int gr = row0 + r0 + i;
      if (gr < n) {
        float4 o = acc3[i];
        o.x += bv.x; o.y += bv.y; o.z += bv.z; o.w += bv.w;
        *(float4*)&p[(size_t)gr * 64 + c0] = o;
      }
    }
  }
}

extern "C" void kernel_launch(void* const* d_in, const int* in_sizes, int n_in,
                              void* d_out, int out_size, void* d_ws, size_t ws_size,
                              hipStream_t stream) {
  const float* x   = (const float*)d_in[0];
  const int*   ei  = (const int*)d_in[1];
  const float* W1  = (const float*)d_in[2];
  const float* b1  = (const float*)d_in[3];
  const float* W2  = (const float*)d_in[4];
  const float* b2  = (const float*)d_in[5];
  const float* Wp1 = (const float*)d_in[6];
  const float* bp1 = (const float*)d_in[7];
  const float* Wp2 = (const float*)d_in[8];
  const float* bp2 = (const float*)d_in[9];

  int n = in_sizes[0] / DIN;   // 50000
  int e = in_sizes[1] / 2;     // 800000
  const int* src = ei;
  const int* dst = ei + e;

  int nblkE = (e + ETILE - 1) / ETILE;            // 196
  int nbBins = (n + BIN_NODES - 1) / BIN_NODES;   // 391
  int gG = (n + 127) / 128;                       // 391

  // workspace layout (non-overlapping; ws is ~268MB)
  char* ws = (char*)d_ws;
  __half* gtab   = (__half*)ws;                            // [0, 6.4MB)   g1, later ah
  __half* htab   = (__half*)(ws + ((size_t)7 << 20));      // [7, 13.4MB)  h
  char*   ctrl   = ws + ((size_t)14 << 20);                // [14MB, ...)
  int*    binTot = (int*)(ctrl);                           // 512 i32
  int*    binOff = (int*)(ctrl + 4096);                    // 513 i32
  int*    binCur = (int*)(ctrl + 8192);                    // 512 i32
  int*    off    = (int*)(ctrl + 16384);                   // (n+1) i32 (~200KB)
  float*  dinv   = (float*)(ctrl + 16384 + (1 << 18));     // n f32
  int*    sp     = (int*)(ctrl + 16384 + (2 << 18));       // e i32 = 3.2MB
  int*    srcs   = sp + e;                                 // e i32 = 3.2MB (ends ~21MB)

  float* zout = (float*)d_out;
  float* pout = zout + (size_t)n * DH;

  // 0) zero bin totals (kernel, capture-safe)
  k_zero<<<1, 512, 0, stream>>>(binTot, NBINS);

  // A) gemm1 (x@W1 -> fp16 g1)  ||  bin histogram
  k_fusedA<<<gG + nblkE, 256, 0, stream>>>(x, W1, gtab, dst, binTot, n, e, gG);

  // B) scan bins
  k_binscan<<<1, 512, 0, stream>>>(binTot, binOff, binCur, e);

  // C) scatter edges into bin-grouped order
  k_scatter2<<<nblkE, 256, 0, stream>>>(src, dst, binCur, sp, e);

  // D) per-bin CSR: off, dinv, srcs
  k_bincsr<<<nbBins, 256, 0, stream>>>(sp, binOff, off, dinv, srcs, n, e);

  // E) h = relu(agg(g1) + b1) -> htab (fp16)
  k_agg<<<(n + 3) / 4, 256, 0, stream>>>(gtab, off, srcs, dinv, b1, htab, n, 1);

  // F) ah = agg(h) -> gtab (fp16; g1 dead)
  k_agg<<<(n + 3) / 4, 256, 0, stream>>>(htab, off, srcs, dinv, nullptr, gtab, n, 0);

  // G) z = ah@W2+b2 (write) ; p = relu(z@Wp1+bp1)@Wp2+bp2 (write)
  k_head3<<<gG, 256, 0, stream>>>(gtab, W2, b2, Wp1, bp1, Wp2, bp2, zout, pout, n);
}